// Round 4
// baseline (187.254 us; speedup 1.0000x reference)
//
#include <hip/hip_runtime.h>
#include <stdint.h>

#define DIM   128
#define KCOLS 65536
#define BB    1024
#define LL    512
#define PSZ   8388608
#define INV_T (1.0f / 0.09f)
#define MOM   0.7f

// output layout (float32 elements, concatenated in return order)
#define OUT_LOGITS 0
#define OUT_LABELS (BB * LL)                    // 524288
#define OUT_QUEUE  (BB * LL + BB)               // 525312
#define OUT_PARAMK (BB * LL + BB + DIM * KCOLS) // 8913920

// ws layout (bytes)
#define WS_QT 0   // bf16 queueT [KCOLS][DIM] = 16 MiB

__device__ inline unsigned short f32_to_bf16(float f) {
    uint32_t u = __float_as_uint(f);
    uint32_t r = (u + 0x7fffu + ((u >> 16) & 1u)) >> 16;
    return (unsigned short)r;
}

// Fused: read queue once (float4-coalesced); write new_queue (float4) AND
// bf16 transposed qt[KCOLS][DIM] (uint4 rows), via LDS tile.
// Key normalization is done INLINE (cooperatively) for the <=16 blocks whose
// column range intersects [start, start+BB).
__global__ void __launch_bounds__(256)
queue_fused_kernel(const float* __restrict__ queue,
                   const float* __restrict__ keys,
                   const int* __restrict__ ptr_p,
                   float* __restrict__ outq,
                   unsigned short* __restrict__ qt) {
    __shared__ float tile[64][DIM + 1];  // [k][d], ~33 KB
    __shared__ float invn_s[64];
    int k0 = blockIdx.x * 64;
    int t  = threadIdx.x;
    int ptr   = ptr_p[0];
    int start = min(max(ptr, 0), KCOLS - BB);  // dynamic_update_slice clamp

    // cooperative inv-norms for the key rows this block will write (if any)
    {
        int row_local = t >> 2;       // 0..63 -> column k0+row_local
        int l4        = t & 3;        // 32-dim slice
        int c = k0 + row_local;
        if (c >= start && c < start + BB) {
            const float4* kr =
                (const float4*)&keys[(size_t)(c - start) * DIM + l4 * 32];
            float s = 0.f;
#pragma unroll
            for (int i = 0; i < 8; ++i) {
                float4 v = kr[i];
                s += v.x * v.x + v.y * v.y + v.z * v.z + v.w * v.w;
            }
            s += __shfl_xor(s, 1, 64);
            s += __shfl_xor(s, 2, 64);
            if (l4 == 0) invn_s[row_local] = 1.0f / sqrtf(s);
        }
    }
    __syncthreads();

    int lane16 = t & 15;
    int hi     = t >> 4;       // 0..15
    int kq     = lane16 * 4;   // column offset within tile, step 4
#pragma unroll
    for (int p = 0; p < 8; ++p) {
        int d = p * 16 + hi;
        float4 v = *(const float4*)&queue[(size_t)d * KCOLS + k0 + kq];
        float vv[4] = {v.x, v.y, v.z, v.w};
#pragma unroll
        for (int j = 0; j < 4; ++j) {
            tile[kq + j][d] = vv[j];           // original value for qt
            int col = k0 + kq + j;
            if (col >= start && col < start + BB)
                vv[j] = keys[(size_t)(col - start) * DIM + d] * invn_s[kq + j];
        }
        float4 w = {vv[0], vv[1], vv[2], vv[3]};
        *(float4*)&outq[(size_t)d * KCOLS + k0 + kq] = w;
    }
    __syncthreads();
    // transpose out: each lane packs 8 consecutive d of one k-row -> uint4
    int d0 = lane16 * 8;
#pragma unroll
    for (int ki = 0; ki < 4; ++ki) {
        int kl = hi + ki * 16;  // 0..63
        float f[8];
#pragma unroll
        for (int j = 0; j < 8; ++j) f[j] = tile[kl][d0 + j];
        uint4 o;
        o.x = (uint32_t)f32_to_bf16(f[0]) | ((uint32_t)f32_to_bf16(f[1]) << 16);
        o.y = (uint32_t)f32_to_bf16(f[2]) | ((uint32_t)f32_to_bf16(f[3]) << 16);
        o.z = (uint32_t)f32_to_bf16(f[4]) | ((uint32_t)f32_to_bf16(f[5]) << 16);
        o.w = (uint32_t)f32_to_bf16(f[6]) | ((uint32_t)f32_to_bf16(f[7]) << 16);
        *(uint4*)&qt[(size_t)(k0 + kl) * DIM + d0] = o;
    }
}

// 8-term bf16 dot-accumulate against a qreg slice
#define DOT8(uu, qo, dst) {                                    \
    float acc = 0.f;                                           \
    acc += qreg[(qo) + 0] * __uint_as_float((uu).x << 16);     \
    acc += qreg[(qo) + 1] * __uint_as_float((uu).x & 0xffff0000u); \
    acc += qreg[(qo) + 2] * __uint_as_float((uu).y << 16);     \
    acc += qreg[(qo) + 3] * __uint_as_float((uu).y & 0xffff0000u); \
    acc += qreg[(qo) + 4] * __uint_as_float((uu).z << 16);     \
    acc += qreg[(qo) + 5] * __uint_as_float((uu).z & 0xffff0000u); \
    acc += qreg[(qo) + 6] * __uint_as_float((uu).w << 16);     \
    acc += qreg[(qo) + 7] * __uint_as_float((uu).w & 0xffff0000u); \
    (dst) = acc; }

// Fused logits + momentum-param update, 1:8 dispatch-striped AND XCD-sharded.
//   bid % 9 == 0 -> logits group g = bid/9  (1024 blocks)
//   else         -> param chunk (bid/9)*8 + bid%9 - 1  (8192 blocks)
// Logits group g: xcd = g & 7 (stripe period 9 == 1 mod 8, so consecutive
// logits blocks round-robin XCDs and g&7 tracks the actual XCD), rows
// b_base..b_base+7 with b_base = (g>>3)*8. The block processes ONLY indices
// in its XCD's 2 MB qt shard (idx>>13 == xcd) -> after warmup every gather
// is an L2 hit, no cross-XCD/LLC traffic. 8 rows/block keeps per-quartet
// work at ~8 entries (2-wide pipelined loop, 8 x 16B loads in flight).
// Quartet->row assignment is static so q stays in registers.
__global__ void __launch_bounds__(256)
logits_param_kernel(const float* __restrict__ q,
                    const unsigned short* __restrict__ qt,
                    const int* __restrict__ sidx,
                    const float* __restrict__ pq,
                    const float* __restrict__ pk,
                    float* __restrict__ out) {
    int t   = threadIdx.x;
    int bid = blockIdx.x;
    int g   = bid / 9;
    int rem = bid - g * 9;

    if (rem != 0) {
        // ---- momentum param path ----
        int gid  = (g * 8 + rem - 1) * 256 + t;
        float4 a = ((const float4*)pq)[gid];
        float4 c = ((const float4*)pk)[gid];
        float4 r;
        r.x = c.x * MOM + a.x * (1.0f - MOM);
        r.y = c.y * MOM + a.y * (1.0f - MOM);
        r.z = c.z * MOM + a.z * (1.0f - MOM);
        r.w = c.w * MOM + a.w * (1.0f - MOM);
        ((float4*)(out + OUT_PARAMK))[gid] = r;
        if (gid < BB) out[OUT_LABELS + gid] = 0.0f;
        return;
    }

    // ---- logits path ----
    int xcd    = g & 7;
    int b_base = (g >> 3) * 8;

    __shared__ unsigned short lsl[8][128];  // matching l values per row
    __shared__ unsigned short lsi[8][128];  // idx low-13 bits per row
    __shared__ int cnt8[8];
    if (t < 8) cnt8[t] = 0;

    int quarter = t & 3;        // 16B piece of each 64B segment
    int qrt     = t >> 2;       // quartet 0..63
    int sub     = qrt & 7;      // quartet slot within its row
    int b_local = qrt >> 3;     // 0..7  (wave-aligned: 32 lanes per row)
    int b       = b_base + b_local;

    // --- normalize q[b] (32 lanes per row), fold 1/T into qreg ---
    float qreg[32];
    {
        int half = t & 31;
        float4 v = ((const float4*)(q + (size_t)b * DIM))[half];
        float s  = v.x * v.x + v.y * v.y + v.z * v.z + v.w * v.w;
        s += __shfl_xor(s, 1, 64);
        s += __shfl_xor(s, 2, 64);
        s += __shfl_xor(s, 4, 64);
        s += __shfl_xor(s, 8, 64);
        s += __shfl_xor(s, 16, 64);
        float inv = rsqrtf(s) * INV_T;
        const float* qb = q + (size_t)b * DIM;
#pragma unroll
        for (int j = 0; j < 4; ++j) {
            const float4* pp = (const float4*)(qb + j * 32 + quarter * 8);
            float4 v0 = pp[0], v1 = pp[1];
            qreg[j * 8 + 0] = v0.x * inv; qreg[j * 8 + 1] = v0.y * inv;
            qreg[j * 8 + 2] = v0.z * inv; qreg[j * 8 + 3] = v0.w * inv;
            qreg[j * 8 + 4] = v1.x * inv; qreg[j * 8 + 5] = v1.y * inv;
            qreg[j * 8 + 6] = v1.z * inv; qreg[j * 8 + 7] = v1.w * inv;
        }
    }
    __syncthreads();   // cnt8 zeroing visible

    // --- parallel filter: 4096 indices via int4, LDS atomics into 8 lists ---
    {
        const int4* s4 = (const int4*)(sidx + (size_t)b_base * LL);
#pragma unroll
        for (int c = 0; c < 4; ++c) {
            int chunk = t + c * 256;        // 0..1023
            int4 v  = s4[chunk];
            int bl  = chunk >> 7;           // 128 int4-chunks per row
            int l0  = (chunk & 127) * 4;
            int ids[4] = {v.x, v.y, v.z, v.w};
#pragma unroll
            for (int j = 0; j < 4; ++j) {
                int idx = ids[j];
                if ((idx >> 13) == xcd) {
                    int p = atomicAdd(&cnt8[bl], 1);
                    if (p < 128) {
                        lsl[bl][p] = (unsigned short)(l0 + j);
                        lsi[bl][p] = (unsigned short)(idx & 0x1FFF);
                    }
                }
            }
        }
    }
    __syncthreads();
    int cb = min(cnt8[b_local], 128);

    // --- gather loop, 2-wide software pipeline (8 x 16B loads in flight) ---
    const unsigned short* qbase = qt + ((size_t)xcd << 13) * DIM;
    float* outl = out + OUT_LOGITS + (size_t)b * LL;

    for (int i = sub; i < cb; i += 16) {
        int iB  = i + 8;
        int lA  = lsl[b_local][i];
        const uint4* pA =
            (const uint4*)(qbase + (size_t)lsi[b_local][i] * DIM) + quarter;
        uint4 a0 = pA[0], a1 = pA[4], a2 = pA[8], a3 = pA[12];
        bool vB = iB < cb;
        int lB = 0;
        uint4 b0, b1, b2, b3;
        if (vB) {
            lB = lsl[b_local][iB];
            const uint4* pB =
                (const uint4*)(qbase + (size_t)lsi[b_local][iB] * DIM) + quarter;
            b0 = pB[0]; b1 = pB[4]; b2 = pB[8]; b3 = pB[12];
        }
        {
            float s0, s1, s2, s3;
            DOT8(a0,  0, s0);
            DOT8(a1,  8, s1);
            DOT8(a2, 16, s2);
            DOT8(a3, 24, s3);
            float s = (s0 + s1) + (s2 + s3);
            s += __shfl_xor(s, 1, 64);
            s += __shfl_xor(s, 2, 64);
            if (quarter == 0) outl[lA] = s;
        }
        if (vB) {
            float s0, s1, s2, s3;
            DOT8(b0,  0, s0);
            DOT8(b1,  8, s1);
            DOT8(b2, 16, s2);
            DOT8(b3, 24, s3);
            float s = (s0 + s1) + (s2 + s3);
            s += __shfl_xor(s, 1, 64);
            s += __shfl_xor(s, 2, 64);
            if (quarter == 0) outl[lB] = s;
        }
    }
}

extern "C" void kernel_launch(void* const* d_in, const int* in_sizes, int n_in,
                              void* d_out, int out_size, void* d_ws, size_t ws_size,
                              hipStream_t stream) {
    const float* q     = (const float*)d_in[0];
    const float* queue = (const float*)d_in[1];
    const float* keys  = (const float*)d_in[2];
    const float* pq    = (const float*)d_in[3];
    const float* pk    = (const float*)d_in[4];
    const int*   sidx  = (const int*)d_in[5];
    const int*   ptr_p = (const int*)d_in[6];
    float* out = (float*)d_out;

    unsigned short* ws_qt = (unsigned short*)((char*)d_ws + WS_QT);

    // 1) fused queue copy/overwrite (inline key-norm) + bf16 transpose
    queue_fused_kernel<<<KCOLS / 64, 256, 0, stream>>>(queue, keys, ptr_p,
                                                       out + OUT_QUEUE, ws_qt);
    // 2) striped + XCD-sharded fused gathered dots + momentum param update
    logits_param_kernel<<<9 * BB, 256, 0, stream>>>(q, ws_qt, sidx,
                                                    pq, pk, out);
}

// Round 6
// 180.195 us; speedup vs baseline: 1.0392x; 1.0392x over previous
//
#include <hip/hip_runtime.h>
#include <stdint.h>

#define DIM   128
#define KCOLS 65536
#define BB    1024
#define LL    512
#define PSZ   8388608
#define INV_T (1.0f / 0.09f)
#define MOM   0.7f

// output layout (float32 elements, concatenated in return order)
#define OUT_LOGITS 0
#define OUT_LABELS (BB * LL)                    // 524288
#define OUT_QUEUE  (BB * LL + BB)               // 525312
#define OUT_PARAMK (BB * LL + BB + DIM * KCOLS) // 8913920

// ws layout (bytes)
#define WS_QT 0   // bf16 queueT [KCOLS][DIM] = 16 MiB

typedef float f32x4 __attribute__((ext_vector_type(4)));

__device__ inline unsigned short f32_to_bf16(float f) {
    uint32_t u = __float_as_uint(f);
    uint32_t r = (u + 0x7fffu + ((u >> 16) & 1u)) >> 16;
    return (unsigned short)r;
}

// Fused: read queue once (nontemporal f32x4); write new_queue (nontemporal)
// AND bf16 transposed qt[KCOLS][DIM] (CACHEABLE uint4 -> stays in this XCD's
// L2 for the logits dispatch), via LDS tile. Key normalization inline.
__global__ void __launch_bounds__(256)
queue_fused_kernel(const float* __restrict__ queue,
                   const float* __restrict__ keys,
                   const int* __restrict__ ptr_p,
                   float* __restrict__ outq,
                   unsigned short* __restrict__ qt) {
    __shared__ float tile[64][DIM + 1];  // [k][d], ~33 KB
    __shared__ float invn_s[64];
    int k0 = blockIdx.x * 64;
    int t  = threadIdx.x;
    int ptr   = ptr_p[0];
    int start = min(max(ptr, 0), KCOLS - BB);  // dynamic_update_slice clamp

    // cooperative inv-norms for the key rows this block will write (if any)
    {
        int row_local = t >> 2;       // 0..63 -> column k0+row_local
        int l4        = t & 3;        // 32-dim slice
        int c = k0 + row_local;
        if (c >= start && c < start + BB) {
            const float4* kr =
                (const float4*)&keys[(size_t)(c - start) * DIM + l4 * 32];
            float s = 0.f;
#pragma unroll
            for (int i = 0; i < 8; ++i) {
                float4 v = kr[i];
                s += v.x * v.x + v.y * v.y + v.z * v.z + v.w * v.w;
            }
            s += __shfl_xor(s, 1, 64);
            s += __shfl_xor(s, 2, 64);
            if (l4 == 0) invn_s[row_local] = 1.0f / sqrtf(s);
        }
    }
    __syncthreads();

    int lane16 = t & 15;
    int hi     = t >> 4;       // 0..15
    int kq     = lane16 * 4;   // column offset within tile, step 4
#pragma unroll
    for (int p = 0; p < 8; ++p) {
        int d = p * 16 + hi;
        f32x4 v = __builtin_nontemporal_load(
            (const f32x4*)&queue[(size_t)d * KCOLS + k0 + kq]);
        float vv[4] = {v.x, v.y, v.z, v.w};
#pragma unroll
        for (int j = 0; j < 4; ++j) {
            tile[kq + j][d] = vv[j];           // original value for qt
            int col = k0 + kq + j;
            if (col >= start && col < start + BB)
                vv[j] = keys[(size_t)(col - start) * DIM + d] * invn_s[kq + j];
        }
        f32x4 w = {vv[0], vv[1], vv[2], vv[3]};
        __builtin_nontemporal_store(
            w, (f32x4*)&outq[(size_t)d * KCOLS + k0 + kq]);
    }
    __syncthreads();
    // transpose out: each lane packs 8 consecutive d of one k-row -> uint4
    // (CACHEABLE store: this XCD's L2 keeps its 64-col stripes for phase 2)
    int d0 = lane16 * 8;
#pragma unroll
    for (int ki = 0; ki < 4; ++ki) {
        int kl = hi + ki * 16;  // 0..63
        float f[8];
#pragma unroll
        for (int j = 0; j < 8; ++j) f[j] = tile[kl][d0 + j];
        uint4 o;
        o.x = (uint32_t)f32_to_bf16(f[0]) | ((uint32_t)f32_to_bf16(f[1]) << 16);
        o.y = (uint32_t)f32_to_bf16(f[2]) | ((uint32_t)f32_to_bf16(f[3]) << 16);
        o.z = (uint32_t)f32_to_bf16(f[4]) | ((uint32_t)f32_to_bf16(f[5]) << 16);
        o.w = (uint32_t)f32_to_bf16(f[6]) | ((uint32_t)f32_to_bf16(f[7]) << 16);
        *(uint4*)&qt[(size_t)(k0 + kl) * DIM + d0] = o;
    }
}

// 8-term bf16 dot-accumulate against a qreg slice
#define DOT8(uu, qo, dst) {                                    \
    float acc = 0.f;                                           \
    acc += qreg[(qo) + 0] * __uint_as_float((uu).x << 16);     \
    acc += qreg[(qo) + 1] * __uint_as_float((uu).x & 0xffff0000u); \
    acc += qreg[(qo) + 2] * __uint_as_float((uu).y << 16);     \
    acc += qreg[(qo) + 3] * __uint_as_float((uu).y & 0xffff0000u); \
    acc += qreg[(qo) + 4] * __uint_as_float((uu).z << 16);     \
    acc += qreg[(qo) + 5] * __uint_as_float((uu).z & 0xffff0000u); \
    acc += qreg[(qo) + 6] * __uint_as_float((uu).w << 16);     \
    acc += qreg[(qo) + 7] * __uint_as_float((uu).w & 0xffff0000u); \
    (dst) = acc; }

// Fused logits + momentum-param update, 1:8 dispatch-striped AND
// STRIPE-MATCHED XCD-sharded:
//   queue_fused block bid wrote columns [bid*64, bid*64+64) on XCD bid%8,
//   so qt stripe s = (k>>6)&7 lives in XCD s's L2 (2 MB per XCD, cacheable
//   writes, param stream is nontemporal so it stays resident).
//   Logits group g (bid=9g -> XCD g%8) processes ONLY indices with
//   (idx>>6)&7 == g&7  -> every gather is a LOCAL L2 hit.
// 8 rows/block keeps ~8 entries/quartet (2-wide pipeline, 8 loads in flight).
__global__ void __launch_bounds__(256)
logits_param_kernel(const float* __restrict__ q,
                    const unsigned short* __restrict__ qt,
                    const int* __restrict__ sidx,
                    const float* __restrict__ pq,
                    const float* __restrict__ pk,
                    float* __restrict__ out) {
    int t   = threadIdx.x;
    int bid = blockIdx.x;
    int g   = bid / 9;
    int rem = bid - g * 9;

    if (rem != 0) {
        // ---- momentum param path (fully nontemporal: don't touch L2's qt) --
        int gid  = (g * 8 + rem - 1) * 256 + t;
        f32x4 a = __builtin_nontemporal_load((const f32x4*)pq + gid);
        f32x4 c = __builtin_nontemporal_load((const f32x4*)pk + gid);
        f32x4 r = c * MOM + a * (1.0f - MOM);
        __builtin_nontemporal_store(r, (f32x4*)(out + OUT_PARAMK) + gid);
        if (gid < BB) out[OUT_LABELS + gid] = 0.0f;
        return;
    }

    // ---- logits path ----
    int xcd    = g & 7;
    int b_base = (g >> 3) * 8;

    __shared__ uint32_t lst[8][128];   // (l<<16)|idx per row
    __shared__ int cnt8[8];
    if (t < 8) cnt8[t] = 0;

    int quarter = t & 3;        // 16B piece of each 64B segment
    int qrt     = t >> 2;       // quartet 0..63
    int sub     = qrt & 7;      // quartet slot within its row
    int b_local = qrt >> 3;     // 0..7  (wave-aligned: 32 lanes per row)
    int b       = b_base + b_local;

    // --- normalize q[b] (32 lanes per row), fold 1/T into qreg ---
    float qreg[32];
    {
        int half = t & 31;
        float4 v = ((const float4*)(q + (size_t)b * DIM))[half];
        float s  = v.x * v.x + v.y * v.y + v.z * v.z + v.w * v.w;
        s += __shfl_xor(s, 1, 64);
        s += __shfl_xor(s, 2, 64);
        s += __shfl_xor(s, 4, 64);
        s += __shfl_xor(s, 8, 64);
        s += __shfl_xor(s, 16, 64);
        float inv = rsqrtf(s) * INV_T;
        const float* qb = q + (size_t)b * DIM;
#pragma unroll
        for (int j = 0; j < 4; ++j) {
            const float4* pp = (const float4*)(qb + j * 32 + quarter * 8);
            float4 v0 = pp[0], v1 = pp[1];
            qreg[j * 8 + 0] = v0.x * inv; qreg[j * 8 + 1] = v0.y * inv;
            qreg[j * 8 + 2] = v0.z * inv; qreg[j * 8 + 3] = v0.w * inv;
            qreg[j * 8 + 4] = v1.x * inv; qreg[j * 8 + 5] = v1.y * inv;
            qreg[j * 8 + 6] = v1.z * inv; qreg[j * 8 + 7] = v1.w * inv;
        }
    }
    __syncthreads();   // cnt8 zeroing visible

    // --- parallel filter: 4096 indices via int4, LDS atomics into 8 lists ---
    {
        const int4* s4 = (const int4*)(sidx + (size_t)b_base * LL);
#pragma unroll
        for (int c = 0; c < 4; ++c) {
            int chunk = t + c * 256;        // 0..1023
            int4 v  = s4[chunk];
            int bl  = chunk >> 7;           // 128 int4-chunks per row
            int l0  = (chunk & 127) * 4;
            int ids[4] = {v.x, v.y, v.z, v.w};
#pragma unroll
            for (int j = 0; j < 4; ++j) {
                int idx = ids[j];
                if (((idx >> 6) & 7) == xcd) {   // stripe-matched shard
                    int p = atomicAdd(&cnt8[bl], 1);
                    if (p < 128)
                        lst[bl][p] = ((uint32_t)(l0 + j) << 16) | (uint32_t)idx;
                }
            }
        }
    }
    __syncthreads();
    int cb = min(cnt8[b_local], 128);

    // --- gather loop, 2-wide software pipeline (8 x 16B loads in flight) ---
    float* outl = out + OUT_LOGITS + (size_t)b * LL;

    for (int i = sub; i < cb; i += 16) {
        int iB  = i + 8;
        uint32_t eA = lst[b_local][i];
        const uint4* pA =
            (const uint4*)(qt + (size_t)(eA & 0xffffu) * DIM) + quarter;
        uint4 a0 = pA[0], a1 = pA[4], a2 = pA[8], a3 = pA[12];
        bool vB = iB < cb;
        uint32_t eB = 0;
        uint4 b0, b1, b2, b3;
        if (vB) {
            eB = lst[b_local][iB];
            const uint4* pB =
                (const uint4*)(qt + (size_t)(eB & 0xffffu) * DIM) + quarter;
            b0 = pB[0]; b1 = pB[4]; b2 = pB[8]; b3 = pB[12];
        }
        {
            float s0, s1, s2, s3;
            DOT8(a0,  0, s0);
            DOT8(a1,  8, s1);
            DOT8(a2, 16, s2);
            DOT8(a3, 24, s3);
            float s = (s0 + s1) + (s2 + s3);
            s += __shfl_xor(s, 1, 64);
            s += __shfl_xor(s, 2, 64);
            if (quarter == 0) outl[eA >> 16] = s;
        }
        if (vB) {
            float s0, s1, s2, s3;
            DOT8(b0,  0, s0);
            DOT8(b1,  8, s1);
            DOT8(b2, 16, s2);
            DOT8(b3, 24, s3);
            float s = (s0 + s1) + (s2 + s3);
            s += __shfl_xor(s, 1, 64);
            s += __shfl_xor(s, 2, 64);
            if (quarter == 0) outl[eB >> 16] = s;
        }
    }
}

extern "C" void kernel_launch(void* const* d_in, const int* in_sizes, int n_in,
                              void* d_out, int out_size, void* d_ws, size_t ws_size,
                              hipStream_t stream) {
    const float* q     = (const float*)d_in[0];
    const float* queue = (const float*)d_in[1];
    const float* keys  = (const float*)d_in[2];
    const float* pq    = (const float*)d_in[3];
    const float* pk    = (const float*)d_in[4];
    const int*   sidx  = (const int*)d_in[5];
    const int*   ptr_p = (const int*)d_in[6];
    float* out = (float*)d_out;

    unsigned short* ws_qt = (unsigned short*)((char*)d_ws + WS_QT);

    // 1) fused queue copy/overwrite (inline key-norm) + bf16 transpose
    //    (qt cacheable, queue/new_queue nontemporal)
    queue_fused_kernel<<<KCOLS / 64, 256, 0, stream>>>(queue, keys, ptr_p,
                                                       out + OUT_QUEUE, ws_qt);
    // 2) striped + stripe-matched-sharded gathered dots + nt param update
    logits_param_kernel<<<9 * BB, 256, 0, stream>>>(q, ws_qt, sidx,
                                                    pq, pk, out);
}

// Round 8
// 178.277 us; speedup vs baseline: 1.0504x; 1.0108x over previous
//
#include <hip/hip_runtime.h>
#include <stdint.h>

#define DIM   128
#define KCOLS 65536
#define BB    1024
#define LL    512
#define PSZ   8388608
#define INV_T (1.0f / 0.09f)
#define MOM   0.7f

// output layout (float32 elements, concatenated in return order)
#define OUT_LOGITS 0
#define OUT_LABELS (BB * LL)                    // 524288
#define OUT_QUEUE  (BB * LL + BB)               // 525312
#define OUT_PARAMK (BB * LL + BB + DIM * KCOLS) // 8913920

// ws layout (bytes)
#define WS_QT 0   // bf16 queueT [KCOLS][DIM] = 16 MiB

typedef float f32x4 __attribute__((ext_vector_type(4)));

__device__ inline unsigned short f32_to_bf16(float f) {
    uint32_t u = __float_as_uint(f);
    uint32_t r = (u + 0x7fffu + ((u >> 16) & 1u)) >> 16;
    return (unsigned short)r;
}

// Kernel 1: ALL pure-streaming work, 1:1 block-interleaved.
//   odd  bid -> param momentum chunk (8 f32x4/thread, nontemporal)
//   even bid -> queue tile: read queue (nt), write new_queue (nt, with
//               inline-normalized key overwrite) + bf16 transposed qt
//               (CACHEABLE -> resident in L2/LLC for kernel 2).
// Rationale: both streams are BW-bound; overlapping them is purely additive
// (~177 MB / 6.2 TB/s ~= 29 us) and keeps the HBM-saturating param stream
// AWAY from kernel 2's latency-sensitive gathers.
__global__ void __launch_bounds__(256)
queue_param_kernel(const float* __restrict__ queue,
                   const float* __restrict__ keys,
                   const int* __restrict__ ptr_p,
                   const float* __restrict__ pq,
                   const float* __restrict__ pk,
                   float* __restrict__ out,
                   unsigned short* __restrict__ qt) {
    int bid = blockIdx.x;
    int t   = threadIdx.x;

    if (bid & 1) {
        // ---- param momentum path (nontemporal; 1024 blocks x 2048 f32x4) --
        int c = bid >> 1;
        const f32x4* pq4 = (const f32x4*)pq;
        const f32x4* pk4 = (const f32x4*)pk;
        f32x4* paramk4   = (f32x4*)(out + OUT_PARAMK);
#pragma unroll
        for (int i = 0; i < 8; ++i) {
            int gid = c * 2048 + i * 256 + t;
            f32x4 a = __builtin_nontemporal_load(pq4 + gid);
            f32x4 b = __builtin_nontemporal_load(pk4 + gid);
            f32x4 r = b * MOM + a * (1.0f - MOM);
            __builtin_nontemporal_store(r, paramk4 + gid);
        }
        if (c == 0) {
            f32x4 z = {0.f, 0.f, 0.f, 0.f};
            ((f32x4*)(out + OUT_LABELS))[t] = z;
        }
        return;
    }

    // ---- queue tile path ----
    __shared__ float tile[64][DIM + 1];  // [k][d], ~33 KB
    __shared__ float invn_s[64];
    int k0 = (bid >> 1) * 64;
    int ptr   = ptr_p[0];
    int start = min(max(ptr, 0), KCOLS - BB);  // dynamic_update_slice clamp

    // cooperative inv-norms for the key rows this block will write (if any)
    {
        int row_local = t >> 2;       // 0..63 -> column k0+row_local
        int l4        = t & 3;        // 32-dim slice
        int c = k0 + row_local;
        if (c >= start && c < start + BB) {
            const float4* kr =
                (const float4*)&keys[(size_t)(c - start) * DIM + l4 * 32];
            float s = 0.f;
#pragma unroll
            for (int i = 0; i < 8; ++i) {
                float4 v = kr[i];
                s += v.x * v.x + v.y * v.y + v.z * v.z + v.w * v.w;
            }
            s += __shfl_xor(s, 1, 64);
            s += __shfl_xor(s, 2, 64);
            if (l4 == 0) invn_s[row_local] = 1.0f / sqrtf(s);
        }
    }
    __syncthreads();

    int lane16 = t & 15;
    int hi     = t >> 4;       // 0..15
    int kq     = lane16 * 4;   // column offset within tile, step 4
#pragma unroll
    for (int p = 0; p < 8; ++p) {
        int d = p * 16 + hi;
        f32x4 v = __builtin_nontemporal_load(
            (const f32x4*)&queue[(size_t)d * KCOLS + k0 + kq]);
        float vv[4] = {v.x, v.y, v.z, v.w};
#pragma unroll
        for (int j = 0; j < 4; ++j) {
            tile[kq + j][d] = vv[j];           // original value for qt
            int col = k0 + kq + j;
            if (col >= start && col < start + BB)
                vv[j] = keys[(size_t)(col - start) * DIM + d] * invn_s[kq + j];
        }
        f32x4 w = {vv[0], vv[1], vv[2], vv[3]};
        __builtin_nontemporal_store(
            w, (f32x4*)&out[OUT_QUEUE + (size_t)d * KCOLS + k0 + kq]);
    }
    __syncthreads();
    // transpose out: each lane packs 8 consecutive d of one k-row -> uint4
    // (cacheable store: qt stays L2/LLC-resident for kernel 2)
    int d0 = lane16 * 8;
#pragma unroll
    for (int ki = 0; ki < 4; ++ki) {
        int kl = hi + ki * 16;  // 0..63
        float f[8];
#pragma unroll
        for (int j = 0; j < 8; ++j) f[j] = tile[kl][d0 + j];
        uint4 o;
        o.x = (uint32_t)f32_to_bf16(f[0]) | ((uint32_t)f32_to_bf16(f[1]) << 16);
        o.y = (uint32_t)f32_to_bf16(f[2]) | ((uint32_t)f32_to_bf16(f[3]) << 16);
        o.z = (uint32_t)f32_to_bf16(f[4]) | ((uint32_t)f32_to_bf16(f[5]) << 16);
        o.w = (uint32_t)f32_to_bf16(f[6]) | ((uint32_t)f32_to_bf16(f[7]) << 16);
        *(uint4*)&qt[(size_t)(k0 + kl) * DIM + d0] = o;
    }
}

// 8-term bf16 dot-accumulate against a qreg slice
#define DOT8(uu, qo, dst) {                                    \
    float acc = 0.f;                                           \
    acc += qreg[(qo) + 0] * __uint_as_float((uu).x << 16);     \
    acc += qreg[(qo) + 1] * __uint_as_float((uu).x & 0xffff0000u); \
    acc += qreg[(qo) + 2] * __uint_as_float((uu).y << 16);     \
    acc += qreg[(qo) + 3] * __uint_as_float((uu).y & 0xffff0000u); \
    acc += qreg[(qo) + 4] * __uint_as_float((uu).z << 16);     \
    acc += qreg[(qo) + 5] * __uint_as_float((uu).z & 0xffff0000u); \
    acc += qreg[(qo) + 6] * __uint_as_float((uu).w << 16);     \
    acc += qreg[(qo) + 7] * __uint_as_float((uu).w & 0xffff0000u); \
    (dst) = acc; }

// Kernel 2: logits ONLY, against a quiet memory system.
// One block per batch row. Each 4-lane quartet owns 8 entries with a 4-deep
// rolling uint4 window -> 16 independent 16B loads in flight per lane.
// Line-coalesced: a quartet's 4 lanes read quarter*16B of ONE 64B segment.
// Uniform trip count (no divergence), no filter, no LDS atomics.
__global__ void __launch_bounds__(256)
logits_kernel(const float* __restrict__ q,
              const unsigned short* __restrict__ qt,
              const int* __restrict__ sidx,
              float* __restrict__ out) {
    int b = blockIdx.x;
    int t = threadIdx.x;

    __shared__ int sl[LL];
#pragma unroll
    for (int l = t; l < LL; l += 256) sl[l] = sidx[b * LL + l];

    int quarter = t & 3;   // which 16B piece of each 64B segment
    int grp     = t >> 2;  // 0..63: which l-slot within each pass

    // normalize q[b] in-register; fold 1/T in.
    // Lane holds dims  j*32 + quarter*8 + {0..7}  (slot-major gather layout).
    float qreg[32];
    {
        const float* qb = q + (size_t)b * DIM;
        float s = 0.f;
#pragma unroll
        for (int j = 0; j < 4; ++j) {
            const float4* pp = (const float4*)(qb + j * 32 + quarter * 8);
            float4 v0 = pp[0], v1 = pp[1];
            qreg[j * 8 + 0] = v0.x; qreg[j * 8 + 1] = v0.y;
            qreg[j * 8 + 2] = v0.z; qreg[j * 8 + 3] = v0.w;
            qreg[j * 8 + 4] = v1.x; qreg[j * 8 + 5] = v1.y;
            qreg[j * 8 + 6] = v1.z; qreg[j * 8 + 7] = v1.w;
            s += v0.x * v0.x + v0.y * v0.y + v0.z * v0.z + v0.w * v0.w;
            s += v1.x * v1.x + v1.y * v1.y + v1.z * v1.z + v1.w * v1.w;
        }
        s += __shfl_xor(s, 1, 64);
        s += __shfl_xor(s, 2, 64);
        float inv = rsqrtf(s) * INV_T;
#pragma unroll
        for (int i = 0; i < 32; ++i) qreg[i] *= inv;
    }
    __syncthreads();

    // this quartet's 8 gather indices (LDS broadcast reads)
    int idxs[8];
#pragma unroll
    for (int e = 0; e < 8; ++e) idxs[e] = sl[grp + (e << 6)];

    // 4-deep rolling window; entry e's 256B row read as 4 slot-major uint4s:
    // lane address = idx*256B + j*64B + quarter*16B
    uint4 w[4][4];
#pragma unroll
    for (int e = 0; e < 4; ++e) {
        const uint4* p = (const uint4*)(qt + (size_t)idxs[e] * DIM) + quarter;
        w[e][0] = p[0]; w[e][1] = p[4]; w[e][2] = p[8]; w[e][3] = p[12];
    }
#pragma unroll
    for (int e = 0; e < 8; ++e) {
        const int slot = e & 3;
        uint4 t0 = w[slot][0], t1 = w[slot][1], t2 = w[slot][2], t3 = w[slot][3];
        if (e < 4) {  // refill the slot just drained (consumed at e+4)
            const uint4* p =
                (const uint4*)(qt + (size_t)idxs[e + 4] * DIM) + quarter;
            w[slot][0] = p[0]; w[slot][1] = p[4];
            w[slot][2] = p[8]; w[slot][3] = p[12];
        }
        float s0, s1, s2, s3;
        DOT8(t0,  0, s0);
        DOT8(t1,  8, s1);
        DOT8(t2, 16, s2);
        DOT8(t3, 24, s3);
        float s = (s0 + s1) + (s2 + s3);
        s += __shfl_xor(s, 1, 64);
        s += __shfl_xor(s, 2, 64);
        if (quarter == 0)
            out[OUT_LOGITS + (size_t)b * LL + grp + (e << 6)] = s;
    }
}

extern "C" void kernel_launch(void* const* d_in, const int* in_sizes, int n_in,
                              void* d_out, int out_size, void* d_ws, size_t ws_size,
                              hipStream_t stream) {
    const float* q     = (const float*)d_in[0];
    const float* queue = (const float*)d_in[1];
    const float* keys  = (const float*)d_in[2];
    const float* pq    = (const float*)d_in[3];
    const float* pk    = (const float*)d_in[4];
    const int*   sidx  = (const int*)d_in[5];
    const int*   ptr_p = (const int*)d_in[6];
    float* out = (float*)d_out;

    unsigned short* ws_qt = (unsigned short*)((char*)d_ws + WS_QT);

    // 1) ALL streaming: queue copy/overwrite + bf16 transpose + param update
    queue_param_kernel<<<2 * (KCOLS / 64), 256, 0, stream>>>(
        queue, keys, ptr_p, pq, pk, out, ws_qt);
    // 2) pure gather logits against a quiet memory system
    logits_kernel<<<BB, 256, 0, stream>>>(q, ws_qt, sidx, out + OUT_LOGITS);
}